// Round 1
// baseline (323.539 us; speedup 1.0000x reference)
//
#include <hip/hip_runtime.h>

// TMoE layer: y = SCALING * (softmax(x@route_w^T) gated low-rank mixture)
// Factorization: g[t, e*64+r] = route[t,e]*c[t,r]*SCALING;  y = g @ Bflat^T
//   Bflat[o][e*64+r] = B[e][o][r]
//
// Pipeline (all bf16 MFMA, fp32 accumulate):
//   conv_w1 : W1 = [A(64 rows); route_w(8); zeros(8)] -> bf16 [80][1024]
//   conv_b  : B -> Bflat bf16 [1024][512]
//   k1      : C1 = X*W1^T (MFMA), softmax+gate epilogue -> g bf16 [32768][512]
//   k2      : y = g @ Bflat^T (128x128 tile MFMA GEMM), fp32 out

#define NTOK    32768
#define DIM     1024
#define NW1     80          // 64 c-rows + 8 router rows + 8 zero pad
#define KC      32          // K-chunk per MFMA step
#define GDIM    512         // E*R
#define OUTD    1024
#define SCALING 0.25f

typedef __bf16 bf16x8 __attribute__((ext_vector_type(8)));
typedef float  f32x4  __attribute__((ext_vector_type(4)));

static __device__ __forceinline__ unsigned short f2bf(float f) {
    union { float f; unsigned u; } v; v.f = f;
    unsigned r = v.u + 0x7FFFu + ((v.u >> 16) & 1u);   // RNE
    return (unsigned short)(r >> 16);
}

static __device__ __forceinline__ unsigned pack2(float a, float b) {
    return (unsigned)f2bf(a) | ((unsigned)f2bf(b) << 16);
}

// ---------------- weight conversion ----------------
__global__ __launch_bounds__(256) void conv_w1(const float* __restrict__ A,
                                               const float* __restrict__ Rw,
                                               unsigned short* __restrict__ w1) {
    int i = blockIdx.x * 256 + threadIdx.x;
    if (i >= NW1 * DIM) return;
    int row = i >> 10, col = i & (DIM - 1);
    float v = 0.0f;
    if (row < 64)      v = A[(row << 10) + col];
    else if (row < 72) v = Rw[((row - 64) << 10) + col];
    w1[i] = f2bf(v);
}

__global__ __launch_bounds__(256) void conv_b(const float* __restrict__ B,
                                              unsigned short* __restrict__ bc) {
    int i = blockIdx.x * 256 + threadIdx.x;     // i = o*512 + e*64 + r
    if (i >= OUTD * GDIM) return;
    int o = i >> 9, er = i & 511;
    int e = er >> 6, r = er & 63;
    bc[i] = f2bf(B[(e << 16) + (o << 6) + r]);  // B[e][o][r], strides 65536/64/1
}

// ---------------- k1: routing + compress + gate ----------------
// 128 tokens per block, 4 waves. C1 = X*W1^T via 16x16x32 bf16 MFMA.
// Wave w handles token rows [w*32, w*32+32) x all 80 outputs (2x5 frags).
__global__ __launch_bounds__(256) void k1_route_compress(
        const float* __restrict__ x,
        const unsigned short* __restrict__ w1,
        unsigned short* __restrict__ g) {
    __shared__ unsigned short sX[128][40];   // stride 40 halfwords = 80 B (2-way max aliasing)
    __shared__ unsigned short sW[NW1][40];
    __shared__ float cAll[128][84];          // c[0..63], logits[64..71], pad
    __shared__ float rL[128][8];             // route * SCALING / denom

    const int tid  = threadIdx.x;
    const int wave = tid >> 6;
    const int lane = tid & 63;
    const int quad = lane >> 4;
    const int l16  = lane & 15;
    const int t0   = blockIdx.x << 7;

    f32x4 acc[2][5];
#pragma unroll
    for (int i = 0; i < 2; ++i)
#pragma unroll
        for (int n = 0; n < 5; ++n) acc[i][n] = (f32x4){0.f, 0.f, 0.f, 0.f};

    for (int k0 = 0; k0 < DIM; k0 += KC) {
        // stage X tile 128x32 fp32 -> bf16 LDS (1024 float4 loads, 4/thread)
#pragma unroll
        for (int i = 0; i < 4; ++i) {
            int idx = tid + (i << 8);
            int row = idx >> 3;
            int kq  = idx & 7;
            const float4 v = *(const float4*)(x + (size_t)(t0 + row) * DIM + k0 + (kq << 2));
            ushort4 b;
            b.x = f2bf(v.x); b.y = f2bf(v.y); b.z = f2bf(v.z); b.w = f2bf(v.w);
            *(ushort4*)(&sX[row][kq << 2]) = b;
        }
        // stage W1 tile 80x32 bf16 (640 ushort4 loads)
#pragma unroll
        for (int i = 0; i < 3; ++i) {
            int idx = tid + (i << 8);
            if (idx < 640) {
                int row = idx >> 3;
                int kq  = idx & 7;
                *(ushort4*)(&sW[row][kq << 2]) =
                    *(const ushort4*)(w1 + (row << 10) + k0 + (kq << 2));
            }
        }
        __syncthreads();
        bf16x8 af[2], bfr[5];
#pragma unroll
        for (int i = 0; i < 2; ++i)
            af[i] = *(const bf16x8*)(&sX[(wave << 5) + (i << 4) + l16][quad << 3]);
#pragma unroll
        for (int n = 0; n < 5; ++n)
            bfr[n] = *(const bf16x8*)(&sW[(n << 4) + l16][quad << 3]);
#pragma unroll
        for (int i = 0; i < 2; ++i)
#pragma unroll
            for (int n = 0; n < 5; ++n)
                acc[i][n] = __builtin_amdgcn_mfma_f32_16x16x32_bf16(af[i], bfr[n], acc[i][n], 0, 0, 0);
        __syncthreads();
    }

    // D layout: col = lane&15, row = quad*4 + reg (m89/m91 verified)
#pragma unroll
    for (int i = 0; i < 2; ++i)
#pragma unroll
        for (int n = 0; n < 5; ++n)
#pragma unroll
            for (int r = 0; r < 4; ++r)
                cAll[(wave << 5) + (i << 4) + (quad << 2) + r][(n << 4) + l16] = acc[i][n][r];
    __syncthreads();

    // softmax over 8 logits, fold SCALING into route weights
    if (tid < 128) {
        float lg[8]; float m = -1e30f;
#pragma unroll
        for (int e = 0; e < 8; ++e) { lg[e] = cAll[tid][64 + e]; m = fmaxf(m, lg[e]); }
        float s = 0.f;
#pragma unroll
        for (int e = 0; e < 8; ++e) { lg[e] = expf(lg[e] - m); s += lg[e]; }
        float inv = SCALING / s;
#pragma unroll
        for (int e = 0; e < 8; ++e) rL[tid][e] = lg[e] * inv;
    }
    __syncthreads();

    // g[t][e*64+r] = route[e]*c[r], coalesced 16B stores (8 bf16/thread/iter)
#pragma unroll
    for (int i = 0; i < 32; ++i) {
        int flat = tid + (i << 8);       // 0..8191
        int t    = flat >> 6;
        int er8  = flat & 63;            // which 8-element chunk of 512
        int e    = er8 >> 3;
        int r0   = (er8 & 7) << 3;
        float rt = rL[t][e];
        uint4 pk;
        pk.x = pack2(rt * cAll[t][r0 + 0], rt * cAll[t][r0 + 1]);
        pk.y = pack2(rt * cAll[t][r0 + 2], rt * cAll[t][r0 + 3]);
        pk.z = pack2(rt * cAll[t][r0 + 4], rt * cAll[t][r0 + 5]);
        pk.w = pack2(rt * cAll[t][r0 + 6], rt * cAll[t][r0 + 7]);
        *(uint4*)(g + (size_t)(t0 + t) * GDIM + (er8 << 3)) = pk;
    }
}

// ---------------- k2: y = g @ Bflat^T ----------------
// 128x128 tile, 4 waves, each 64x64 (4x4 frags of 16x16x32). K = 512.
__global__ __launch_bounds__(256) void k2_up(
        const unsigned short* __restrict__ g,
        const unsigned short* __restrict__ bc,
        float* __restrict__ y) {
    __shared__ unsigned short sA[128][40];
    __shared__ unsigned short sB[128][40];

    const int tid  = threadIdx.x;
    const int wave = tid >> 6;
    const int lane = tid & 63;
    const int quad = lane >> 4;
    const int l16  = lane & 15;

    const int mt = blockIdx.x & 255;
    const int nt = blockIdx.x >> 8;
    const int m0 = mt << 7;
    const int n0 = nt << 7;
    const int mo = (wave & 1) << 6;
    const int no = (wave >> 1) << 6;

    f32x4 acc[4][4];
#pragma unroll
    for (int i = 0; i < 4; ++i)
#pragma unroll
        for (int j = 0; j < 4; ++j) acc[i][j] = (f32x4){0.f, 0.f, 0.f, 0.f};

    for (int k0 = 0; k0 < GDIM; k0 += KC) {
#pragma unroll
        for (int i = 0; i < 2; ++i) {
            int idx = tid + (i << 8);    // 0..511
            int row = idx >> 2;          // 0..127
            int kq  = idx & 3;           // 16B chunk within 32 halfwords
            *(uint4*)(&sA[row][kq << 3]) =
                *(const uint4*)(g + (size_t)(m0 + row) * GDIM + k0 + (kq << 3));
            *(uint4*)(&sB[row][kq << 3]) =
                *(const uint4*)(bc + (size_t)(n0 + row) * GDIM + k0 + (kq << 3));
        }
        __syncthreads();
        bf16x8 af[4], bfr[4];
#pragma unroll
        for (int i = 0; i < 4; ++i)
            af[i] = *(const bf16x8*)(&sA[mo + (i << 4) + l16][quad << 3]);
#pragma unroll
        for (int j = 0; j < 4; ++j)
            bfr[j] = *(const bf16x8*)(&sB[no + (j << 4) + l16][quad << 3]);
#pragma unroll
        for (int i = 0; i < 4; ++i)
#pragma unroll
            for (int j = 0; j < 4; ++j)
                acc[i][j] = __builtin_amdgcn_mfma_f32_16x16x32_bf16(af[i], bfr[j], acc[i][j], 0, 0, 0);
        __syncthreads();
    }

#pragma unroll
    for (int i = 0; i < 4; ++i)
#pragma unroll
        for (int j = 0; j < 4; ++j)
#pragma unroll
            for (int r = 0; r < 4; ++r) {
                int row = m0 + mo + (i << 4) + (quad << 2) + r;
                int col = n0 + no + (j << 4) + l16;
                y[(size_t)row * OUTD + col] = acc[i][j][r];
            }
}

extern "C" void kernel_launch(void* const* d_in, const int* in_sizes, int n_in,
                              void* d_out, int out_size, void* d_ws, size_t ws_size,
                              hipStream_t stream) {
    const float* x  = (const float*)d_in[0];   // [8,4096,1024]
    const float* rw = (const float*)d_in[1];   // [8,1024]
    const float* A  = (const float*)d_in[2];   // [64,1024]
    const float* B  = (const float*)d_in[3];   // [8,1024,64]
    float* y = (float*)d_out;                  // [8,4096,1024] fp32

    // ws layout (bf16 elements): g [32768][512], w1 [80][1024], bc [1024][512]
    unsigned short* g  = (unsigned short*)d_ws;
    unsigned short* w1 = g + (size_t)NTOK * GDIM;
    unsigned short* bc = w1 + NW1 * DIM;

    conv_w1<<<(NW1 * DIM + 255) / 256, 256, 0, stream>>>(A, rw, w1);
    conv_b<<<(OUTD * GDIM + 255) / 256, 256, 0, stream>>>(B, bc);
    k1_route_compress<<<NTOK / 128, 256, 0, stream>>>(x, w1, g);
    k2_up<<<(NTOK / 128) * (OUTD / 128), 256, 0, stream>>>(g, bc, y);
}

// Round 4
// 322.898 us; speedup vs baseline: 1.0020x; 1.0020x over previous
//
#include <hip/hip_runtime.h>

// TMoE layer: y = SCALING * (softmax(x@route_w^T) gated low-rank mixture)
// Factorization: g[t, e*64+r] = route[t,e]*c[t,r]*SCALING;  y = g @ Bflat^T
//   Bflat[o][e*64+r] = B[e][o][r]
//
// R3: full revert to the R0-proven conv_w1/conv_b/k1 (R1/R2's merged-conv +
// barrier-free k1 set contains an unlocated bug). Single change vs R0:
// k2 uses KC=64 (two 32-wide MFMA sub-chunks per barrier pair, 32 MFMAs
// between barriers instead of 16), LDS row stride 72 halfwords (16B aligned).

#define NTOK    32768
#define DIM     1024
#define NW1     80          // 64 c-rows + 8 router rows + 8 zero pad
#define KC      32
#define GDIM    512         // E*R
#define OUTD    1024
#define SCALING 0.25f

typedef __bf16 bf16x8 __attribute__((ext_vector_type(8)));
typedef float  f32x4  __attribute__((ext_vector_type(4)));

static __device__ __forceinline__ unsigned short f2bf(float f) {
    union { float f; unsigned u; } v; v.f = f;
    unsigned r = v.u + 0x7FFFu + ((v.u >> 16) & 1u);   // RNE
    return (unsigned short)(r >> 16);
}

// ---------------- weight conversion (R0-proven) ----------------
__global__ __launch_bounds__(256) void conv_w1(const float* __restrict__ A,
                                               const float* __restrict__ Rw,
                                               unsigned short* __restrict__ w1) {
    int i = blockIdx.x * 256 + threadIdx.x;
    if (i >= NW1 * DIM) return;
    int row = i >> 10, col = i & (DIM - 1);
    float v = 0.0f;
    if (row < 64)      v = A[(row << 10) + col];
    else if (row < 72) v = Rw[((row - 64) << 10) + col];
    w1[i] = f2bf(v);
}

__global__ __launch_bounds__(256) void conv_b(const float* __restrict__ B,
                                              unsigned short* __restrict__ bc) {
    int i = blockIdx.x * 256 + threadIdx.x;     // i = o*512 + e*64 + r
    if (i >= OUTD * GDIM) return;
    int o = i >> 9, er = i & 511;
    int e = er >> 6, r = er & 63;
    bc[i] = f2bf(B[(e << 16) + (o << 6) + r]);  // B[e][o][r], strides 65536/64/1
}

// ---------------- k1: routing + compress + gate (R0-proven) ----------------
__global__ __launch_bounds__(256) void k1_route_compress(
        const float* __restrict__ x,
        const unsigned short* __restrict__ w1,
        unsigned short* __restrict__ g) {
    __shared__ unsigned short sX[128][40];
    __shared__ unsigned short sW[NW1][40];
    __shared__ float cAll[128][84];
    __shared__ float rL[128][8];

    const int tid  = threadIdx.x;
    const int wave = tid >> 6;
    const int lane = tid & 63;
    const int quad = lane >> 4;
    const int l16  = lane & 15;
    const int t0   = blockIdx.x << 7;

    f32x4 acc[2][5];
#pragma unroll
    for (int i = 0; i < 2; ++i)
#pragma unroll
        for (int n = 0; n < 5; ++n) acc[i][n] = (f32x4){0.f, 0.f, 0.f, 0.f};

    for (int k0 = 0; k0 < DIM; k0 += KC) {
#pragma unroll
        for (int i = 0; i < 4; ++i) {
            int idx = tid + (i << 8);
            int row = idx >> 3;
            int kq  = idx & 7;
            const float4 v = *(const float4*)(x + (size_t)(t0 + row) * DIM + k0 + (kq << 2));
            ushort4 b;
            b.x = f2bf(v.x); b.y = f2bf(v.y); b.z = f2bf(v.z); b.w = f2bf(v.w);
            *(ushort4*)(&sX[row][kq << 2]) = b;
        }
#pragma unroll
        for (int i = 0; i < 3; ++i) {
            int idx = tid + (i << 8);
            if (idx < 640) {
                int row = idx >> 3;
                int kq  = idx & 7;
                *(ushort4*)(&sW[row][kq << 2]) =
                    *(const ushort4*)(w1 + (row << 10) + k0 + (kq << 2));
            }
        }
        __syncthreads();
        bf16x8 af[2], bfr[5];
#pragma unroll
        for (int i = 0; i < 2; ++i)
            af[i] = *(const bf16x8*)(&sX[(wave << 5) + (i << 4) + l16][quad << 3]);
#pragma unroll
        for (int n = 0; n < 5; ++n)
            bfr[n] = *(const bf16x8*)(&sW[(n << 4) + l16][quad << 3]);
#pragma unroll
        for (int i = 0; i < 2; ++i)
#pragma unroll
            for (int n = 0; n < 5; ++n)
                acc[i][n] = __builtin_amdgcn_mfma_f32_16x16x32_bf16(af[i], bfr[n], acc[i][n], 0, 0, 0);
        __syncthreads();
    }

    // D layout: col = lane&15, row = quad*4 + reg
#pragma unroll
    for (int i = 0; i < 2; ++i)
#pragma unroll
        for (int n = 0; n < 5; ++n)
#pragma unroll
            for (int r = 0; r < 4; ++r)
                cAll[(wave << 5) + (i << 4) + (quad << 2) + r][(n << 4) + l16] = acc[i][n][r];
    __syncthreads();

    if (tid < 128) {
        float lg[8]; float m = -1e30f;
#pragma unroll
        for (int e = 0; e < 8; ++e) { lg[e] = cAll[tid][64 + e]; m = fmaxf(m, lg[e]); }
        float s = 0.f;
#pragma unroll
        for (int e = 0; e < 8; ++e) { lg[e] = expf(lg[e] - m); s += lg[e]; }
        float inv = SCALING / s;
#pragma unroll
        for (int e = 0; e < 8; ++e) rL[tid][e] = lg[e] * inv;
    }
    __syncthreads();

#pragma unroll
    for (int i = 0; i < 32; ++i) {
        int flat = tid + (i << 8);       // 0..8191
        int t    = flat >> 6;
        int er8  = flat & 63;
        int e    = er8 >> 3;
        int r0   = (er8 & 7) << 3;
        float rt = rL[t][e];
        bf16x8 pk;
#pragma unroll
        for (int j = 0; j < 8; ++j) pk[j] = (__bf16)(rt * cAll[t][r0 + j]);
        *(bf16x8*)(g + (size_t)(t0 + t) * GDIM + (er8 << 3)) = pk;
    }
}

// ---------------- k2: y = g @ Bflat^T ----------------
// 128x128 tile, 4 waves x (64x64 = 4x4 frags). R3 change: KC=64 —
// stage 128x64 tiles (row stride 72 halfwords, 16B-aligned), 32 MFMAs
// per barrier pair (2 k-subchunks), 8 iterations instead of 16.
__global__ __launch_bounds__(256) void k2_up(
        const unsigned short* __restrict__ g,
        const unsigned short* __restrict__ bc,
        float* __restrict__ y) {
    __shared__ unsigned short sA[128][72];
    __shared__ unsigned short sB[128][72];

    const int tid  = threadIdx.x;
    const int wave = tid >> 6;
    const int lane = tid & 63;
    const int quad = lane >> 4;
    const int l16  = lane & 15;

    const int m0 = (blockIdx.x & 255) << 7;
    const int n0 = (blockIdx.x >> 8) << 7;
    const int mo = (wave & 1) << 6;
    const int no = (wave >> 1) << 6;

    f32x4 acc[4][4];
#pragma unroll
    for (int i = 0; i < 4; ++i)
#pragma unroll
        for (int j = 0; j < 4; ++j) acc[i][j] = (f32x4){0.f, 0.f, 0.f, 0.f};

    for (int k0 = 0; k0 < GDIM; k0 += 64) {
        // stage A,B 128x64 tiles: 1024 uint4 chunks each, 4 per thread
#pragma unroll
        for (int i = 0; i < 4; ++i) {
            int idx = tid + (i << 8);    // 0..1023
            int row = idx >> 3;          // 0..127
            int kq  = idx & 7;           // 16B chunk within 64 halfwords
            *(uint4*)(&sA[row][kq << 3]) =
                *(const uint4*)(g + (size_t)(m0 + row) * GDIM + k0 + (kq << 3));
            *(uint4*)(&sB[row][kq << 3]) =
                *(const uint4*)(bc + (size_t)(n0 + row) * GDIM + k0 + (kq << 3));
        }
        __syncthreads();
#pragma unroll
        for (int kk = 0; kk < 2; ++kk) {
            bf16x8 af[4], bfr[4];
#pragma unroll
            for (int i = 0; i < 4; ++i)
                af[i] = *(const bf16x8*)(&sA[mo + (i << 4) + l16][(kk << 5) + (quad << 3)]);
#pragma unroll
            for (int j = 0; j < 4; ++j)
                bfr[j] = *(const bf16x8*)(&sB[no + (j << 4) + l16][(kk << 5) + (quad << 3)]);
#pragma unroll
            for (int i = 0; i < 4; ++i)
#pragma unroll
                for (int j = 0; j < 4; ++j)
                    acc[i][j] = __builtin_amdgcn_mfma_f32_16x16x32_bf16(af[i], bfr[j], acc[i][j], 0, 0, 0);
        }
        __syncthreads();
    }

#pragma unroll
    for (int i = 0; i < 4; ++i)
#pragma unroll
        for (int j = 0; j < 4; ++j)
#pragma unroll
            for (int r = 0; r < 4; ++r) {
                int row = m0 + mo + (i << 4) + (quad << 2) + r;
                int col = n0 + no + (j << 4) + l16;
                y[(size_t)row * OUTD + col] = acc[i][j][r];
            }
}

extern "C" void kernel_launch(void* const* d_in, const int* in_sizes, int n_in,
                              void* d_out, int out_size, void* d_ws, size_t ws_size,
                              hipStream_t stream) {
    const float* x  = (const float*)d_in[0];   // [8,4096,1024]
    const float* rw = (const float*)d_in[1];   // [8,1024]
    const float* A  = (const float*)d_in[2];   // [64,1024]
    const float* B  = (const float*)d_in[3];   // [8,1024,64]
    float* y = (float*)d_out;                  // [8,4096,1024] fp32

    unsigned short* g  = (unsigned short*)d_ws;          // [32768][512] bf16
    unsigned short* w1 = g + (size_t)NTOK * GDIM;        // [80][1024] bf16
    unsigned short* bc = w1 + NW1 * DIM;                 // [1024][512] bf16

    conv_w1<<<(NW1 * DIM + 255) / 256, 256, 0, stream>>>(A, rw, w1);
    conv_b<<<(OUTD * GDIM + 255) / 256, 256, 0, stream>>>(B, bc);
    k1_route_compress<<<NTOK / 128, 256, 0, stream>>>(x, w1, g);
    k2_up<<<(NTOK / 128) * (OUTD / 128), 256, 0, stream>>>(g, bc, y);
}